// Round 17
// baseline (105.555 us; speedup 1.0000x reference)
//
#include <hip/hip_runtime.h>
#include <math.h>

// Problem constants (match reference)
#define BATCH    8192
#define FIELDS   32
#define DIM      32
#define NREG     6
#define EPS      1e-5f
#define NBLKA    4096          // K1/K3 blocks: 2 batch rows per block
#define PBASE    64            // ws float offset of per-block partials
#define SCALE_F  (PBASE + 64 * NBLKA)          // ws float offset of scale[32][32]
#define BIAS_F   (SCALE_F + FIELDS * DIM)      // ws float offset of bias[32][32]

// ws layout (floats):
//   [PBASE + slot*NBLKA + blk]  per-block partials, slot = f (sum) or 32+f (sumsq)
//   [SCALE_F + f*32 + d]        istd[f] * coef[f][d]
//   [BIAS_F  + f*32 + d]        -mean[f] * istd[f] * coef[f][d]
// No atomics, no memset: every word is written before it is read.
// K1 stages raw gathered rows INTO the output buffer (final layout), so the
// random gather is paid exactly once; K3 is a pure streaming fma in-place.

// K1: gather + stage raw values to out + per-block per-field partials.
__global__ __launch_bounds__(256) void irazor_stage_stats_kernel(
        const int*   __restrict__ ids,    // [BATCH, FIELDS]
        const float* __restrict__ table,  // [VOCAB, DIM]
        float*       __restrict__ ws,
        float*       __restrict__ out) {  // staging: raw emb in final layout
    const int t   = threadIdx.x;
    const int blk = blockIdx.x;
    const int f   = t >> 3;
    const int vec = t & 7;

    float4* __restrict__ out4 = reinterpret_cast<float4*>(out);
    float s = 0.f, sq = 0.f;
    #pragma unroll
    for (int i = 0; i < 2; ++i) {
        const int id = ids[(blk * 2 + i) * FIELDS + f];
        const float4 v = *reinterpret_cast<const float4*>(
            table + (size_t)id * DIM + vec * 4);
        out4[(size_t)blk * 512 + (size_t)i * 256 + t] = v;   // coalesced stage
        s  += v.x + v.y + v.z + v.w;
        sq += v.x * v.x + v.y * v.y + v.z * v.z + v.w * v.w;
    }

    #pragma unroll
    for (int off = 1; off < 8; off <<= 1) {
        s  += __shfl_xor(s, off);
        sq += __shfl_xor(sq, off);
    }
    if (vec == 0) {                       // threads 0,8,...,248: one per field
        ws[PBASE + f * NBLKA + blk]        = s;
        ws[PBASE + (32 + f) * NBLKA + blk] = sq;
    }
}

// K2: one block per FIELD. Reduce sum+sumsq (2 x 4096 floats), then fold
// normalization + region-softmax coef into per-(f,d) scale/bias.
__global__ __launch_bounds__(256) void irazor_finalize_kernel(
        const float* __restrict__ frw,    // [FIELDS, NREG]
        const float* __restrict__ mask,   // [NREG, DIM]
        float*       __restrict__ ws) {
    const int fld = blockIdx.x;           // 0..31
    const int t   = threadIdx.x;

    const float* __restrict__ ps = ws + PBASE + (size_t)fld * NBLKA;
    const float* __restrict__ pq = ws + PBASE + (size_t)(32 + fld) * NBLKA;
    float a = 0.f, b = 0.f;
    #pragma unroll
    for (int i = 0; i < NBLKA / 256; ++i) {
        a += ps[i * 256 + t];
        b += pq[i * 256 + t];
    }
    #pragma unroll
    for (int off = 1; off < 64; off <<= 1) {
        a += __shfl_xor(a, off);
        b += __shfl_xor(b, off);
    }
    __shared__ float ls[4], lq[4];
    const int wave = t >> 6;
    if ((t & 63) == 0) { ls[wave] = a; lq[wave] = b; }
    __syncthreads();
    const float S  = ls[0] + ls[1] + ls[2] + ls[3];
    const float SQ = lq[0] + lq[1] + lq[2] + lq[3];

    if (t < DIM) {                        // t = dim d
        const float invN = 1.f / (float)(BATCH * DIM);
        const float mean = S * invN;
        const float var  = SQ * invN - mean * mean;
        const float istd = rsqrtf(var + EPS);

        float w[NREG]; float m = -1e30f;
        #pragma unroll
        for (int r = 0; r < NREG; ++r) { w[r] = frw[fld * NREG + r]; m = fmaxf(m, w[r]); }
        float ssum = 0.f;
        #pragma unroll
        for (int r = 0; r < NREG; ++r) { w[r] = __expf(w[r] - m); ssum += w[r]; }
        float c = 0.f;
        #pragma unroll
        for (int r = 0; r < NREG; ++r) c += w[r] * mask[r * DIM + t];
        c /= ssum;

        const float sc = istd * c;
        ws[SCALE_F + fld * DIM + t] = sc;
        ws[BIAS_F  + fld * DIM + t] = -mean * sc;
    }
}

// K3: pure streaming in-place: out = out * scale[f][d] + bias[f][d].
__global__ __launch_bounds__(256) void irazor_apply_kernel(
        const float* __restrict__ ws,
        float*       __restrict__ out) {
    const int t   = threadIdx.x;
    const int blk = blockIdx.x;
    const int f   = t >> 3;
    const int vec = t & 7;

    const float4 sc = *reinterpret_cast<const float4*>(ws + SCALE_F + f * DIM + vec * 4);
    const float4 bi = *reinterpret_cast<const float4*>(ws + BIAS_F  + f * DIM + vec * 4);

    float4* __restrict__ out4 = reinterpret_cast<float4*>(out);
    #pragma unroll
    for (int i = 0; i < 2; ++i) {
        const size_t idx = (size_t)blk * 512 + (size_t)i * 256 + t;
        float4 v = out4[idx];
        float4 o;
        o.x = fmaf(v.x, sc.x, bi.x);
        o.y = fmaf(v.y, sc.y, bi.y);
        o.z = fmaf(v.z, sc.z, bi.z);
        o.w = fmaf(v.w, sc.w, bi.w);
        out4[idx] = o;
    }
}

extern "C" void kernel_launch(void* const* d_in, const int* in_sizes, int n_in,
                              void* d_out, int out_size, void* d_ws, size_t ws_size,
                              hipStream_t stream) {
    const int*   ids   = (const int*)d_in[0];    // [BATCH, FIELDS] int32
    const float* table = (const float*)d_in[1];  // [VOCAB, DIM] f32
    const float* frw   = (const float*)d_in[2];  // [FIELDS, NREG, 1] f32
    const float* mask  = (const float*)d_in[3];  // [NREG, DIM] f32
    float*       out   = (float*)d_out;
    float*       ws    = (float*)d_ws;

    irazor_stage_stats_kernel<<<NBLKA, 256, 0, stream>>>(ids, table, ws, out);
    irazor_finalize_kernel<<<FIELDS, 256, 0, stream>>>(frw, mask, ws);
    irazor_apply_kernel<<<NBLKA, 256, 0, stream>>>(ws, out);
}

// Round 19
// 99.749 us; speedup vs baseline: 1.0582x; 1.0582x over previous
//
#include <hip/hip_runtime.h>
#include <math.h>

// Problem constants (match reference)
#define BATCH    8192
#define FIELDS   32
#define DIM      32
#define NREG     6
#define EPS      1e-5f
#define NBLK2    256           // K2 blocks (field-stats partials)
#define NBLK4    4096          // K4 blocks: 2 batch rows per block
#define VOCAB_N  200000

// ws float offsets (all written before read; no memset needed)
#define PBASE    64                       // partials: [f*NBLK2+blk] sum, +8192 sumsq
#define SCALE_F  (PBASE + 2 * FIELDS * NBLK2)   // 16448: scale[32][32]
#define BIAS_F   (SCALE_F + FIELDS * DIM)       // bias[32][32]
#define RS_F     (BIAS_F + FIELDS * DIM)        // rowsum[VOCAB]
#define RQ_F     (RS_F + VOCAB_N)               // rowsumsq[VOCAB]

// K1: LINEAR table sweep -> per-vocab-row sum & sumsq. No gather.
// 8 lanes per row (float4 each), 32 rows per block.
__global__ __launch_bounds__(256) void irazor_rowstats_kernel(
        const float* __restrict__ table,  // [VOCAB, DIM]
        float*       __restrict__ ws,
        int vocab) {
    const int t   = threadIdx.x;
    const int r   = blockIdx.x * 32 + (t >> 3);
    const int vec = t & 7;
    if (r >= vocab) return;

    const float4 v = *reinterpret_cast<const float4*>(
        table + (size_t)r * DIM + vec * 4);
    float s  = v.x + v.y + v.z + v.w;
    float sq = v.x * v.x + v.y * v.y + v.z * v.z + v.w * v.w;
    #pragma unroll
    for (int off = 1; off < 8; off <<= 1) {
        s  += __shfl_xor(s, off);
        sq += __shfl_xor(sq, off);
    }
    if (vec == 0) {
        ws[RS_F + r] = s;
        ws[RQ_F + r] = sq;
    }
}

// K2: per-field partial sums via rowsum/rowsumsq gather (4B loads from
// ~1.6MB cache-resident arrays). 1024 (b,f) pairs per block, f = t&31.
__global__ __launch_bounds__(256) void irazor_fieldstats_kernel(
        const int*   __restrict__ ids,    // [BATCH*FIELDS]
        float*       __restrict__ ws) {
    const int t    = threadIdx.x;
    const int blk  = blockIdx.x;
    const int lane = t & 63;
    const int wave = t >> 6;

    float s = 0.f, sq = 0.f;
    #pragma unroll
    for (int i = 0; i < 4; ++i) {
        const int id = ids[blk * 1024 + i * 256 + t];   // field = t&31 (stride 256 ≡ 0 mod 32)
        s  += ws[RS_F + id];
        sq += ws[RQ_F + id];
    }
    // lanes l and l+32 share field (t&31)
    s  += __shfl_xor(s, 32);
    sq += __shfl_xor(sq, 32);

    __shared__ float sm[2][4][32];
    if (lane < 32) { sm[0][wave][lane] = s; sm[1][wave][lane] = sq; }
    __syncthreads();
    if (t < 32) {
        ws[PBASE + t * NBLK2 + blk] =
            sm[0][0][t] + sm[0][1][t] + sm[0][2][t] + sm[0][3][t];
    } else if (t < 64) {
        const int f = t - 32;
        ws[PBASE + 8192 + f * NBLK2 + blk] =
            sm[1][0][f] + sm[1][1][f] + sm[1][2][f] + sm[1][3][f];
    }
}

// K3: one block per field: reduce 256 partials, fold mean/var + softmax.mask
// into scale[f][d], bias[f][d].
__global__ __launch_bounds__(256) void irazor_finalize_kernel(
        const float* __restrict__ frw,    // [FIELDS, NREG]
        const float* __restrict__ mask,   // [NREG, DIM]
        float*       __restrict__ ws) {
    const int fld = blockIdx.x;
    const int t   = threadIdx.x;

    float a = ws[PBASE + fld * NBLK2 + t];
    float b = ws[PBASE + 8192 + fld * NBLK2 + t];
    #pragma unroll
    for (int off = 1; off < 64; off <<= 1) {
        a += __shfl_xor(a, off);
        b += __shfl_xor(b, off);
    }
    __shared__ float ls[4], lq[4];
    const int wave = t >> 6;
    if ((t & 63) == 0) { ls[wave] = a; lq[wave] = b; }
    __syncthreads();
    const float S  = ls[0] + ls[1] + ls[2] + ls[3];
    const float SQ = lq[0] + lq[1] + lq[2] + lq[3];

    if (t < DIM) {                        // t = dim d
        const float invN = 1.f / (float)(BATCH * DIM);
        const float mean = S * invN;
        const float var  = SQ * invN - mean * mean;
        const float istd = rsqrtf(var + EPS);

        float w[NREG]; float m = -1e30f;
        #pragma unroll
        for (int r = 0; r < NREG; ++r) { w[r] = frw[fld * NREG + r]; m = fmaxf(m, w[r]); }
        float ssum = 0.f;
        #pragma unroll
        for (int r = 0; r < NREG; ++r) { w[r] = __expf(w[r] - m); ssum += w[r]; }
        float c = 0.f;
        #pragma unroll
        for (int r = 0; r < NREG; ++r) c += w[r] * mask[r * DIM + t];
        c /= ssum;

        const float sc = istd * c;
        ws[SCALE_F + fld * DIM + t] = sc;
        ws[BIAS_F  + fld * DIM + t] = -mean * sc;
    }
}

// K4: the single unavoidable row-gather + fma + coalesced float4 store.
__global__ __launch_bounds__(256) void irazor_out_kernel(
        const int*   __restrict__ ids,
        const float* __restrict__ table,
        const float* __restrict__ ws,
        float*       __restrict__ out) {  // [BATCH, FIELDS, DIM]
    const int t   = threadIdx.x;
    const int blk = blockIdx.x;
    const int f   = t >> 3;
    const int vec = t & 7;

    const float4 sc = *reinterpret_cast<const float4*>(ws + SCALE_F + f * DIM + vec * 4);
    const float4 bi = *reinterpret_cast<const float4*>(ws + BIAS_F  + f * DIM + vec * 4);

    float4* __restrict__ out4 = reinterpret_cast<float4*>(out);
    #pragma unroll
    for (int i = 0; i < 2; ++i) {
        const int id = ids[(blk * 2 + i) * FIELDS + f];
        const float4 v = *reinterpret_cast<const float4*>(
            table + (size_t)id * DIM + vec * 4);
        float4 o;
        o.x = fmaf(v.x, sc.x, bi.x);
        o.y = fmaf(v.y, sc.y, bi.y);
        o.z = fmaf(v.z, sc.z, bi.z);
        o.w = fmaf(v.w, sc.w, bi.w);
        out4[(size_t)blk * 512 + (size_t)i * 256 + t] = o;
    }
}

extern "C" void kernel_launch(void* const* d_in, const int* in_sizes, int n_in,
                              void* d_out, int out_size, void* d_ws, size_t ws_size,
                              hipStream_t stream) {
    const int*   ids   = (const int*)d_in[0];    // [BATCH, FIELDS] int32
    const float* table = (const float*)d_in[1];  // [VOCAB, DIM] f32
    const float* frw   = (const float*)d_in[2];  // [FIELDS, NREG, 1] f32
    const float* mask  = (const float*)d_in[3];  // [NREG, DIM] f32
    float*       out   = (float*)d_out;
    float*       ws    = (float*)d_ws;

    const int vocab = in_sizes[1] / DIM;         // 200000

    irazor_rowstats_kernel<<<(vocab + 31) / 32, 256, 0, stream>>>(table, ws, vocab);
    irazor_fieldstats_kernel<<<NBLK2, 256, 0, stream>>>(ids, ws);
    irazor_finalize_kernel<<<FIELDS, 256, 0, stream>>>(frw, mask, ws);
    irazor_out_kernel<<<NBLK4, 256, 0, stream>>>(ids, table, ws, out);
}